// Round 1
// baseline (22229.944 us; speedup 1.0000x reference)
//
#include <hip/hip_runtime.h>

#define S_LEN 512
#define BATCH 128
#define NH    128
#define NL    3

typedef float f32x4 __attribute__((ext_vector_type(4)));
typedef short bf16x8 __attribute__((ext_vector_type(8)));

__device__ __forceinline__ short f2bf(float f) {
    unsigned u = __builtin_bit_cast(unsigned, f);
    u = (u + 0x7FFFu + ((u >> 16) & 1u)) >> 16;
    return (short)u;
}
__device__ __forceinline__ float bf2f(short s) {
    unsigned u = ((unsigned)(unsigned short)s) << 16;
    return __builtin_bit_cast(float, u);
}
__device__ __forceinline__ float sigm(float x) { return 1.f / (1.f + __expf(-x)); }
__device__ __forceinline__ float tanh_fast(float x) { return 2.f / (1.f + __expf(-2.f * x)) - 1.f; }

// ---------------- K1: xp = x @ lin_w.T + lin_b  ->  bf16 [S*B][H] ----------------
__global__ __launch_bounds__(128) void xp_kernel(const float* __restrict__ x,
        const float* __restrict__ lin_w, const float* __restrict__ lin_b,
        short* __restrict__ xp) {
    __shared__ float xs[8 * 128];
    const int tid = threadIdx.x;
    const long r0 = (long)blockIdx.x * 8;   // 8 (t,b) rows per block
    for (int rr = 0; rr < 8; ++rr)
        xs[rr * 128 + tid] = x[(r0 + rr) * 128 + tid];
    __syncthreads();
    float acc[8];
    float bias = lin_b[tid];
    #pragma unroll
    for (int rr = 0; rr < 8; ++rr) acc[rr] = bias;
    const float* wrow = lin_w + (long)tid * 128;
    for (int k = 0; k < 128; ++k) {
        float wv = wrow[k];
        #pragma unroll
        for (int rr = 0; rr < 8; ++rr) acc[rr] += xs[rr * 128 + k] * wv;
    }
    for (int rr = 0; rr < 8; ++rr)
        xp[(r0 + rr) * 128 + tid] = f2bf(acc[rr]);
}

// ---------------- K2: pack W,U into MFMA B-fragment-linear bf16 ----------------
// Fragment convention (must match A-fragment loads in main kernel):
//   lane l, elem j -> n = ntile*16 + (l&15),  k = ktile*32 + (l>>4)*8 + j
__global__ __launch_bounds__(256) void pack_kernel(const float* __restrict__ W,
        const float* __restrict__ U, short* __restrict__ Wp, short* __restrict__ Up) {
    int id = blockIdx.x * 256 + threadIdx.x;     // 98304 total
    int lane = id & 63;
    int fid = id >> 6;
    int lr = lane & 15, lk = lane >> 4;
    if (fid < 384) {                 // W: fid = (i*32+nt)*4+kt
        int kt = fid & 3, nt = (fid >> 2) & 31, i = fid >> 7;
        const float* src = W + ((long)(i * 512 + nt * 16 + lr) * 128 + kt * 32 + lk * 8);
        short* dst = Wp + (long)fid * 512 + lane * 8;
        #pragma unroll
        for (int j = 0; j < 8; ++j) dst[j] = f2bf(src[j]);
    } else {                         // U: f = (i*32+nt)*12+kt
        int f = fid - 384;
        int kt = f % 12, nt = (f / 12) & 31, i = f / 384;
        const float* src = U + ((long)(i * 512 + nt * 16 + lr) * 384 + kt * 32 + lk * 8);
        short* dst = Up + (long)f * 512 + lane * 8;
        #pragma unroll
        for (int j = 0; j < 8; ++j) dst[j] = f2bf(src[j]);
    }
}

// ---------------- main persistent recurrence: 8 wgs x 16 batch rows ----------------
#define HXS 392   // hx row stride (shorts): 384 + 8 pad -> 4-bank row skew
#define INPS 136  // inp row stride (shorts): 128 + 8 pad
#define GSD 516   // gates row stride (floats): 512 + 4 pad

__global__ __launch_bounds__(1024) void lstm_kernel(
    const short* __restrict__ xp, const short* __restrict__ Wp,
    const short* __restrict__ Up, const float* __restrict__ Gp,
    float* __restrict__ out)
{
    __shared__ short h_lds[NL * 16 * 128];     // carry h (bf16)      12288 B
    __shared__ short hx_lds[16 * HXS];         // gated-h concat      12544 B
    __shared__ short inp_lds[16 * INPS];       // layer input (hy)     4352 B
    __shared__ float gates_lds[16 * GSD];      // gate preacts        33024 B
    __shared__ float G_lds[NL * 128];          //                      1536 B

    const int tid = threadIdx.x;
    const int lane = tid & 63;
    const int w = tid >> 6;          // wave 0..15
    const int lr = lane & 15;        // row/col within 16-tile
    const int lk = lane >> 4;        // k-chunk 0..3
    const int b0 = blockIdx.x * 16;  // batch base
    const int w2 = w * 2;            // this wave owns n-tiles w2, w2+1 per layer

    for (int i = tid; i < NL * 16 * 128; i += 1024) h_lds[i] = 0;
    if (tid < NL * 128) G_lds[tid] = Gp[tid];
    float c_reg[NL][2];
    #pragma unroll
    for (int l = 0; l < NL; ++l) { c_reg[l][0] = 0.f; c_reg[l][1] = 0.f; }
    __syncthreads();

    const short* up_base = Up + lane * 8;
    const short* wp_base = Wp + lane * 8;

    for (int t = 0; t < S_LEN; ++t) {
        // ---- phase 0: per-layer scalar gate, build hx (gated h, bf16) ----
        #pragma unroll
        for (int i = 0; i < 3; ++i) {
            int d = w * 3 + i;           // 48 (l,b) dots
            int l = d >> 4, b = d & 15;
            float h0 = bf2f(h_lds[(l * 16 + b) * 128 + 2 * lane]);
            float h1 = bf2f(h_lds[(l * 16 + b) * 128 + 2 * lane + 1]);
            float p = h0 * G_lds[l * 128 + 2 * lane] + h1 * G_lds[l * 128 + 2 * lane + 1];
            #pragma unroll
            for (int m = 32; m >= 1; m >>= 1) p += __shfl_xor(p, m, 64);
            float gh = sigm(p);
            hx_lds[b * HXS + l * 128 + 2 * lane]     = f2bf(gh * h0);
            hx_lds[b * HXS + l * 128 + 2 * lane + 1] = f2bf(gh * h1);
        }
        __syncthreads();

        // ---- U phase: acc[l][q] = hx @ U[l].T for this wave's n-tiles ----
        f32x4 acc[NL][2];
        #pragma unroll
        for (int l = 0; l < NL; ++l)
            #pragma unroll
            for (int q = 0; q < 2; ++q)
                acc[l][q] = (f32x4){0.f, 0.f, 0.f, 0.f};

        for (int kt = 0; kt < 12; ++kt) {
            bf16x8 a = *(const bf16x8*)&hx_lds[lr * HXS + kt * 32 + lk * 8];
            #pragma unroll
            for (int l = 0; l < NL; ++l)
                #pragma unroll
                for (int q = 0; q < 2; ++q) {
                    bf16x8 bfr = *(const bf16x8*)(up_base + (((l * 32 + w2 + q) * 12) + kt) * 512);
                    acc[l][q] = __builtin_amdgcn_mfma_f32_16x16x32_bf16(a, bfr, acc[l][q], 0, 0, 0);
                }
        }

        const short* xp_t = xp + ((long)(t * BATCH) + b0) * 128;

        // ---- layer chain: W-GEMM + cell ----
        #pragma unroll
        for (int l = 0; l < NL; ++l) {
            #pragma unroll
            for (int kt = 0; kt < 4; ++kt) {
                bf16x8 a;
                if (l == 0) a = *(const bf16x8*)(xp_t + lr * 128 + kt * 32 + lk * 8);
                else        a = *(const bf16x8*)&inp_lds[lr * INPS + kt * 32 + lk * 8];
                #pragma unroll
                for (int q = 0; q < 2; ++q) {
                    bf16x8 bfr = *(const bf16x8*)(wp_base + (((l * 32 + w2 + q) * 4) + kt) * 512);
                    acc[l][q] = __builtin_amdgcn_mfma_f32_16x16x32_bf16(a, bfr, acc[l][q], 0, 0, 0);
                }
            }
            // scatter gate preacts: D[m][n] at lane: m=(lane>>4)*4+r, n=tile*16+(lane&15)
            #pragma unroll
            for (int q = 0; q < 2; ++q)
                #pragma unroll
                for (int r = 0; r < 4; ++r)
                    gates_lds[(lk * 4 + r) * GSD + (w2 + q) * 16 + lr] = acc[l][q][r];
            __syncthreads();

            // cell: 2048 elems / 1024 threads
            #pragma unroll
            for (int s = 0; s < 2; ++s) {
                int e = tid + s * 1024;
                int b = e >> 7, hh = e & 127;
                float ig = sigm(gates_lds[b * GSD + hh]);
                float fg = sigm(gates_lds[b * GSD + 128 + hh]);
                float gg = tanh_fast(gates_lds[b * GSD + 256 + hh]);
                float og = sigm(gates_lds[b * GSD + 384 + hh]);
                float cn = fg * c_reg[l][s] + ig * gg;
                c_reg[l][s] = cn;
                float hy = og * tanh_fast(cn);
                h_lds[(l * 16 + b) * 128 + hh] = f2bf(hy);
                if (l < 2) inp_lds[b * INPS + hh] = f2bf(hy);
                if (t == S_LEN - 1) {
                    out[((l * BATCH + b0 + b) << 7) + hh] = hy;
                    out[(NL * BATCH * NH) + ((l * BATCH + b0 + b) << 7) + hh] = cn;
                }
            }
            __syncthreads();
        }
    }
}

extern "C" void kernel_launch(void* const* d_in, const int* in_sizes, int n_in,
                              void* d_out, int out_size, void* d_ws, size_t ws_size,
                              hipStream_t stream) {
    const float* x     = (const float*)d_in[0];
    const float* lin_w = (const float*)d_in[1];
    const float* lin_b = (const float*)d_in[2];
    const float* W     = (const float*)d_in[3];
    const float* U     = (const float*)d_in[4];
    const float* G     = (const float*)d_in[5];
    float* out = (float*)d_out;

    // workspace layout (all bf16): xp 16 MiB | Wpack 384 KiB | Upack 1.125 MiB
    short* xp = (short*)d_ws;
    short* Wp = (short*)((char*)d_ws + 16777216);
    short* Up = (short*)((char*)d_ws + 16777216 + 393216);

    hipLaunchKernelGGL(xp_kernel,   dim3(8192), dim3(128), 0, stream, x, lin_w, lin_b, xp);
    hipLaunchKernelGGL(pack_kernel, dim3(384),  dim3(256), 0, stream, W, U, Wp, Up);
    hipLaunchKernelGGL(lstm_kernel, dim3(8),    dim3(1024), 0, stream, xp, Wp, Up, G, out);
}

// Round 2
// 22181.651 us; speedup vs baseline: 1.0022x; 1.0022x over previous
//
#include <hip/hip_runtime.h>

#define S_LEN 512
#define BATCH 128
#define NH    128
#define NL    3

typedef float f32x4 __attribute__((ext_vector_type(4)));
typedef short bf16x8 __attribute__((ext_vector_type(8)));

__device__ __forceinline__ short f2bf(float f) {
    unsigned u = __builtin_bit_cast(unsigned, f);
    u = (u + 0x7FFFu + ((u >> 16) & 1u)) >> 16;
    return (short)u;
}
__device__ __forceinline__ float bf2f(short s) {
    unsigned u = ((unsigned)(unsigned short)s) << 16;
    return __builtin_bit_cast(float, u);
}
__device__ __forceinline__ float sigm(float x) { return 1.f / (1.f + __expf(-x)); }
__device__ __forceinline__ float tanh_fast(float x) { return 2.f / (1.f + __expf(-2.f * x)) - 1.f; }

// ---------------- K1: xp = x @ lin_w.T + lin_b  ->  bf16 [S*B][H] ----------------
__global__ __launch_bounds__(128) void xp_kernel(const float* __restrict__ x,
        const float* __restrict__ lin_w, const float* __restrict__ lin_b,
        short* __restrict__ xp) {
    __shared__ float xs[8 * 128];
    const int tid = threadIdx.x;
    const long r0 = (long)blockIdx.x * 8;
    for (int rr = 0; rr < 8; ++rr)
        xs[rr * 128 + tid] = x[(r0 + rr) * 128 + tid];
    __syncthreads();
    float acc[8];
    float bias = lin_b[tid];
    #pragma unroll
    for (int rr = 0; rr < 8; ++rr) acc[rr] = bias;
    const float* wrow = lin_w + (long)tid * 128;
    for (int k = 0; k < 128; ++k) {
        float wv = wrow[k];
        #pragma unroll
        for (int rr = 0; rr < 8; ++rr) acc[rr] += xs[rr * 128 + k] * wv;
    }
    for (int rr = 0; rr < 8; ++rr)
        xp[(r0 + rr) * 128 + tid] = f2bf(acc[rr]);
}

// ---------------- K2: pack W,U wave-contiguous for the main kernel ----------------
// Fragment: lane l, elem j -> n = nt*16 + (l&15), k = kt*32 + (l>>4)*8 + j
// Wp layout: frag f = ((w*3 + l)*4 + kt)*2 + q   (nt = 2w+q), 384 frags
// Up layout: frag f = (w*12 + kt)*6 + (l*2 + q)  (nt = 2w+q), 1152 frags
__global__ __launch_bounds__(256) void pack_kernel(const float* __restrict__ W,
        const float* __restrict__ U, short* __restrict__ Wp, short* __restrict__ Up) {
    int id = blockIdx.x * 256 + threadIdx.x;     // 98304 total = 1536 frags * 64
    int lane = id & 63;
    int fid = id >> 6;
    int lr = lane & 15, lk = lane >> 4;
    if (fid < 384) {
        int q = fid & 1, kt = (fid >> 1) & 3, g = fid >> 3;  // g = w*3 + l
        int l = g % 3, w = g / 3;
        int nt = 2 * w + q;
        const float* src = W + ((long)(l * 512 + nt * 16 + lr) * 128 + kt * 32 + lk * 8);
        short* dst = Wp + (long)fid * 512 + lane * 8;
        #pragma unroll
        for (int j = 0; j < 8; ++j) dst[j] = f2bf(src[j]);
    } else {
        int f = fid - 384;
        int i = f % 6, m = f / 6;
        int kt = m % 12, w = m / 12;
        int l = i >> 1, q = i & 1, nt = 2 * w + q;
        const float* src = U + ((long)(l * 512 + nt * 16 + lr) * 384 + kt * 32 + lk * 8);
        short* dst = Up + (long)f * 512 + lane * 8;
        #pragma unroll
        for (int j = 0; j < 8; ++j) dst[j] = f2bf(src[j]);
    }
}

// ---------------- main persistent recurrence: 8 wgs x 16 batch rows ----------------
#define HXS 392
#define INPS 136
#define GSD 516

__global__ __launch_bounds__(1024) void lstm_kernel(
    const short* __restrict__ xp, const short* __restrict__ Wp,
    const short* __restrict__ Up, const float* __restrict__ Gp,
    float* __restrict__ out)
{
    __shared__ short h_lds[NL * 16 * 128];
    __shared__ short hx_lds[16 * HXS];
    __shared__ short inp_lds[16 * INPS];
    __shared__ float gates_lds[16 * GSD];
    __shared__ float G_lds[NL * 128];

    const int tid = threadIdx.x;
    const int lane = tid & 63;
    const int w = tid >> 6;
    const int lr = lane & 15;
    const int lk = lane >> 4;
    const int b0 = blockIdx.x * 16;
    const int w2 = w * 2;

    for (int i = tid; i < NL * 16 * 128; i += 1024) h_lds[i] = 0;
    if (tid < NL * 128) G_lds[tid] = Gp[tid];
    float c_reg[NL][2];
    #pragma unroll
    for (int l = 0; l < NL; ++l) { c_reg[l][0] = 0.f; c_reg[l][1] = 0.f; }
    __syncthreads();

    const short* UW = Up + (long)w * 72 * 512 + lane * 8;   // this wave's 72 U-frags
    const short* WW = Wp + (long)w * 24 * 512 + lane * 8;   // this wave's 24 W-frags

    for (int t = 0; t < S_LEN; ++t) {
        const short* xp_t = xp + ((long)(t * BATCH) + b0) * 128;

        // ---- early prefetch: xp A-frags (HBM) + layer-0 W frags (L2) ----
        bf16x8 xa[4];
        #pragma unroll
        for (int kt = 0; kt < 4; ++kt)
            xa[kt] = *(const bf16x8*)(xp_t + lr * 128 + kt * 32 + lk * 8);
        bf16x8 wb[8];
        #pragma unroll
        for (int j = 0; j < 8; ++j)
            wb[j] = *(const bf16x8*)(WW + j * 512);

        // ---- phase 0: per-layer scalar gate, build hx ----
        #pragma unroll
        for (int i = 0; i < 3; ++i) {
            int d = w * 3 + i;
            int l = d >> 4, b = d & 15;
            float h0 = bf2f(h_lds[(l * 16 + b) * 128 + 2 * lane]);
            float h1 = bf2f(h_lds[(l * 16 + b) * 128 + 2 * lane + 1]);
            float p = h0 * G_lds[l * 128 + 2 * lane] + h1 * G_lds[l * 128 + 2 * lane + 1];
            #pragma unroll
            for (int m = 32; m >= 1; m >>= 1) p += __shfl_xor(p, m, 64);
            float gh = sigm(p);
            hx_lds[b * HXS + l * 128 + 2 * lane]     = f2bf(gh * h0);
            hx_lds[b * HXS + l * 128 + 2 * lane + 1] = f2bf(gh * h1);
        }
        __syncthreads();

        // ---- U phase: register-double-buffered weight stream ----
        f32x4 acc[NL][2];
        #pragma unroll
        for (int l = 0; l < NL; ++l)
            #pragma unroll
            for (int q = 0; q < 2; ++q)
                acc[l][q] = (f32x4){0.f, 0.f, 0.f, 0.f};

        bf16x8 u0[3], u1[3];
        #pragma unroll
        for (int i = 0; i < 3; ++i) u0[i] = *(const bf16x8*)(UW + i * 512);
        #pragma unroll
        for (int i = 0; i < 3; ++i) u1[i] = *(const bf16x8*)(UW + (3 + i) * 512);

        #pragma unroll
        for (int kt = 0; kt < 12; ++kt) {
            bf16x8 a = *(const bf16x8*)&hx_lds[lr * HXS + kt * 32 + lk * 8];
            acc[0][0] = __builtin_amdgcn_mfma_f32_16x16x32_bf16(a, u0[0], acc[0][0], 0, 0, 0);
            acc[0][1] = __builtin_amdgcn_mfma_f32_16x16x32_bf16(a, u0[1], acc[0][1], 0, 0, 0);
            acc[1][0] = __builtin_amdgcn_mfma_f32_16x16x32_bf16(a, u0[2], acc[1][0], 0, 0, 0);
            if (kt < 11) {
                #pragma unroll
                for (int i = 0; i < 3; ++i)
                    u0[i] = *(const bf16x8*)(UW + ((kt + 1) * 6 + i) * 512);
            }
            acc[1][1] = __builtin_amdgcn_mfma_f32_16x16x32_bf16(a, u1[0], acc[1][1], 0, 0, 0);
            acc[2][0] = __builtin_amdgcn_mfma_f32_16x16x32_bf16(a, u1[1], acc[2][0], 0, 0, 0);
            acc[2][1] = __builtin_amdgcn_mfma_f32_16x16x32_bf16(a, u1[2], acc[2][1], 0, 0, 0);
            if (kt < 11) {
                #pragma unroll
                for (int i = 0; i < 3; ++i)
                    u1[i] = *(const bf16x8*)(UW + ((kt + 1) * 6 + 3 + i) * 512);
            }
        }

        // ---- layer chain: W-GEMM (weights pre-staged in regs) + cell ----
        #pragma unroll
        for (int l = 0; l < NL; ++l) {
            #pragma unroll
            for (int kt = 0; kt < 4; ++kt) {
                bf16x8 a;
                if (l == 0) a = xa[kt];
                else        a = *(const bf16x8*)&inp_lds[lr * INPS + kt * 32 + lk * 8];
                acc[l][0] = __builtin_amdgcn_mfma_f32_16x16x32_bf16(a, wb[kt * 2 + 0], acc[l][0], 0, 0, 0);
                acc[l][1] = __builtin_amdgcn_mfma_f32_16x16x32_bf16(a, wb[kt * 2 + 1], acc[l][1], 0, 0, 0);
            }
            #pragma unroll
            for (int q = 0; q < 2; ++q)
                #pragma unroll
                for (int r = 0; r < 4; ++r)
                    gates_lds[(lk * 4 + r) * GSD + (w2 + q) * 16 + lr] = acc[l][q][r];
            // prefetch next layer's W frags while waiting/cell
            if (l < 2) {
                #pragma unroll
                for (int j = 0; j < 8; ++j)
                    wb[j] = *(const bf16x8*)(WW + ((l + 1) * 8 + j) * 512);
            }
            __syncthreads();

            #pragma unroll
            for (int s = 0; s < 2; ++s) {
                int e = tid + s * 1024;
                int b = e >> 7, hh = e & 127;
                float ig = sigm(gates_lds[b * GSD + hh]);
                float fg = sigm(gates_lds[b * GSD + 128 + hh]);
                float gg = tanh_fast(gates_lds[b * GSD + 256 + hh]);
                float og = sigm(gates_lds[b * GSD + 384 + hh]);
                float cn = fg * c_reg[l][s] + ig * gg;
                c_reg[l][s] = cn;
                float hy = og * tanh_fast(cn);
                h_lds[(l * 16 + b) * 128 + hh] = f2bf(hy);
                if (l < 2) inp_lds[b * INPS + hh] = f2bf(hy);
                if (t == S_LEN - 1) {
                    out[((l * BATCH + b0 + b) << 7) + hh] = hy;
                    out[(NL * BATCH * NH) + ((l * BATCH + b0 + b) << 7) + hh] = cn;
                }
            }
            __syncthreads();
        }
    }
}

extern "C" void kernel_launch(void* const* d_in, const int* in_sizes, int n_in,
                              void* d_out, int out_size, void* d_ws, size_t ws_size,
                              hipStream_t stream) {
    const float* x     = (const float*)d_in[0];
    const float* lin_w = (const float*)d_in[1];
    const float* lin_b = (const float*)d_in[2];
    const float* W     = (const float*)d_in[3];
    const float* U     = (const float*)d_in[4];
    const float* G     = (const float*)d_in[5];
    float* out = (float*)d_out;

    short* xp = (short*)d_ws;
    short* Wp = (short*)((char*)d_ws + 16777216);
    short* Up = (short*)((char*)d_ws + 16777216 + 393216);

    hipLaunchKernelGGL(xp_kernel,   dim3(8192), dim3(128), 0, stream, x, lin_w, lin_b, xp);
    hipLaunchKernelGGL(pack_kernel, dim3(384),  dim3(256), 0, stream, W, U, Wp, Up);
    hipLaunchKernelGGL(lstm_kernel, dim3(8),    dim3(1024), 0, stream, xp, Wp, Up, G, out);
}